// Round 9
// baseline (662.970 us; speedup 1.0000x reference)
//
#include <hip/hip_runtime.h>
#include <hip/hip_bf16.h>

// ---------------- problem constants ----------------
#define QN 1024
#define NDB 200000
#define NDB_PAD 200064        // 3126 subtiles of 64 rows
#define PDBW 257
#define CDIM 256
#define TK 16
#define NEGF (-1e30f)
#define MIN_SIM_C 0.05f
#define MIN_VOTES_C 0.3f

// fused fast path: 256 chunk-blocks (1/CU), 1024 thr (16 waves x 64 q = all queries)
#define NCH 256
#define THETA 0.19f           // P(sim>THETA)=1.18e-3; true 16th-best ~0.236 (fp8 err ~3e-3 -> ~15 sigma)
#define CAPQ 12               // per-(query,chunk) cap (lambda~0.98, P(over)~1e-5 overall -> flag+fallback)
// fallback (round-1, proven) path
#define NCHUNK1 49
#define CPQ1 (NCHUNK1*32)

typedef __attribute__((ext_vector_type(8))) short bf16x8;
typedef __attribute__((ext_vector_type(4))) float f32x4;
typedef __attribute__((ext_vector_type(8))) int   i32x8;
typedef __attribute__((ext_vector_type(4))) int   i32x4;

__device__ __forceinline__ short f2bf(float f) {
  union { float f; unsigned u; } x; x.f = f;
  unsigned u = x.u;
  return (short)((u + 0x7fffu + ((u >> 16) & 1u)) >> 16);  // RNE
}

// pack 4 floats -> 4 fp8 e4m3 bytes (same converter feeds A and B, so any
// consistent lane-position->k mapping cancels in the MFMA dot product)
__device__ __forceinline__ unsigned pk_fp8x4(float a, float b, float c, float d) {
  unsigned w = (unsigned)__builtin_amdgcn_cvt_pk_fp8_f32(a, b, 0, false);
  w = (unsigned)__builtin_amdgcn_cvt_pk_fp8_f32(c, d, (int)w, true);
  return w;
}

// ---------------------------------------------------------------------------
// FUSED kernel: fp32 db -> fp8 reg-staging (swizzled ds_write) + MX-fp8 MFMA
// + register theta-filter + wave-private LDS survivor lists.
// grid 256 (1 block/CU), 1024 thr (16 waves x 64 queries = ALL queries).
// Each db row is read from HBM exactly ONCE (205MB total, overlapped).
// Per iteration: STAGEW(tile s+1 from regs) | LOADT(tile s+2) | MFMA(tile s)
// | filter | lgkm-drain | barrier.  LDS 132KB (static).
// ---------------------------------------------------------------------------
__global__ __launch_bounds__(1024, 1) void sims_fused_kernel(
    const float* __restrict__ qd, const float* __restrict__ pdb,
    unsigned long long* __restrict__ seg_g, unsigned int* __restrict__ cnt_g,
    int* __restrict__ flag)
{
  __shared__ __align__(16) char db_lds[2][64 * 256];   // 32768 B (fp8, swizzled)
  __shared__ unsigned seg_lds[16][64][CAPQ][2];        // 98304 B (wave-private)
  __shared__ int lcnt[16][64];                         // 4096 B (wave-private)

  const int tid  = (int)threadIdx.x;
  const int lane = tid & 63;
  const int wv   = tid >> 6;          // 0..15
  const int cid  = (int)blockIdx.x;   // 0..255
  // chunks 0..53 have 13 subtiles, 54..255 have 12 (covers 3126 subtiles)
  const int nsub = 12 + (cid < 54 ? 1 : 0);
  const int row0 = (12*cid + (cid < 54 ? cid : 54)) << 6;

  if (cid == 0 && tid == 0) *flag = 0;
  lcnt[wv][lane] = 0;   // wave-private, no barrier needed

  const int l15  = lane & 15;
  const int egrp = lane >> 4;         // k-chunk group 0..3 (32 k each)
  const int rowb = egrp << 2;
  const int colb = l15;

  // staging geometry: thread -> (row-in-tile, 16B piece), swizzled dest
  const int srow   = tid >> 4;        // 0..63
  const int spiece = tid & 15;        // 0..15
  const int sdst   = srow*256 + ((spiece ^ (srow & 15)) << 4);

  // ---- Q fragments: fp32 -> fp8 packed i32x8; wave wv owns queries wv*64.. ----
  i32x8 aq[4][2];
  {
    #pragma unroll
    for (int fm = 0; fm < 4; ++fm) {
      const float* qrow = qd + (size_t)(wv*64 + fm*16 + l15)*CDIM;
      #pragma unroll
      for (int kk = 0; kk < 2; ++kk) {
        const float* p = qrow + kk*128 + egrp*32;
        i32x8 a;
        #pragma unroll
        for (int d = 0; d < 8; ++d) {
          float4 x = *(const float4*)(p + d*4);
          a[d] = (int)pk_fp8x4(x.x, x.y, x.z, x.w);
        }
        aq[fm][kk] = a;
      }
    }
  }

  float4 sf0, sf1, sf2, sf3;   // in-flight fp32 staging regs (one tile / thread)
#define LOADT(tile) do { \
    const int _r = row0 + (tile)*64 + srow; \
    if (_r < NDB) { \
      const float* _p = pdb + (size_t)_r*PDBW + spiece*16; \
      sf0 = *(const float4*)(_p);      sf1 = *(const float4*)(_p + 4); \
      sf2 = *(const float4*)(_p + 8);  sf3 = *(const float4*)(_p + 12); \
    } else { \
      sf0 = sf1 = sf2 = sf3 = (float4){0.f, 0.f, 0.f, 0.f}; \
    } \
  } while (0)
#define STAGEW(bufi) do { \
    i32x4 _w; \
    _w[0] = (int)pk_fp8x4(sf0.x, sf0.y, sf0.z, sf0.w); \
    _w[1] = (int)pk_fp8x4(sf1.x, sf1.y, sf1.z, sf1.w); \
    _w[2] = (int)pk_fp8x4(sf2.x, sf2.y, sf2.z, sf2.w); \
    _w[3] = (int)pk_fp8x4(sf3.x, sf3.y, sf3.z, sf3.w); \
    *(i32x4*)(db_lds[(bufi)] + sdst) = _w; \
  } while (0)

  // prologue: tile 0 staged to buf0; tile 1 loads in flight
  LOADT(0);
  STAGEW(0);
  LOADT(1);
  __syncthreads();   // buf0 visible to all waves

  for (int s = 0; s < nsub; ++s) {
    // write tile s+1 into the buffer MFMA-read in iter s-1 (safe: drained at
    // last barrier); issue tile s+2 loads -- a full iteration to land
    if (s + 1 < nsub) {
      STAGEW((s + 1) & 1);             // waits (data-dep) on LOADT(s+1)
      if (s + 2 < nsub) LOADT(s + 2);
    }

    // ---- MFMA: 64q x 64db per wave, K=256 via 2x K=128 MX-fp8 (unit scale) ----
    f32x4 acc[4][4];
    #pragma unroll
    for (int fm = 0; fm < 4; ++fm)
      #pragma unroll
      for (int fn = 0; fn < 4; ++fn)
        acc[fm][fn] = (f32x4){0.f, 0.f, 0.f, 0.f};
    __builtin_amdgcn_s_setprio(1);
    {
      const char* dbt = (const char*)db_lds[s & 1];
      #pragma unroll
      for (int kk = 0; kk < 2; ++kk) {
        #pragma unroll
        for (int fn = 0; fn < 4; ++fn) {
          const char* rowp = dbt + (fn*16 + l15)*256;
          const int mbase = kk*8 + egrp*2;
          i32x4 lo = *(const i32x4*)(rowp + (((mbase    ) ^ l15) << 4));
          i32x4 hi = *(const i32x4*)(rowp + (((mbase + 1) ^ l15) << 4));
          i32x8 b = __builtin_shufflevector(lo, hi, 0, 1, 2, 3, 4, 5, 6, 7);
          #pragma unroll
          for (int fm = 0; fm < 4; ++fm)
            acc[fm][fn] = __builtin_amdgcn_mfma_scale_f32_16x16x128_f8f6f4(
                aq[fm][kk], b, acc[fm][fn],
                0 /*fmtA=fp8*/, 0 /*fmtB=fp8*/,
                0, 0x7F7F7F7Fu /*scaleA=1.0*/, 0, 0x7F7F7F7Fu /*scaleB=1.0*/);
        }
      }
    }
    __builtin_amdgcn_s_setprio(0);

    // ---- theta-filter on fragments; wave-private LDS append ----
    {
      const int idxbase = row0 + s*64;
      #pragma unroll
      for (int fm = 0; fm < 4; ++fm)
        #pragma unroll
        for (int fn = 0; fn < 4; ++fn) {
          const f32x4 a = acc[fm][fn];
          const float m = fmaxf(fmaxf(a[0], a[1]), fmaxf(a[2], a[3]));
          if (m > THETA) {
            #pragma unroll
            for (int j = 0; j < 4; ++j) {
              if (a[j] > THETA) {
                const int ql = fm*16 + rowb + j;
                const int slot = atomicAdd(&lcnt[wv][ql], 1);
                if (slot < CAPQ) {
                  seg_lds[wv][ql][slot][0] = __float_as_uint(a[j]);
                  seg_lds[wv][ql][slot][1] = (unsigned)(idxbase + fn*16 + colb);
                }
              }
            }
          }
        }
    }

    // drain own ds ops, then barrier: makes the buffer rotation hazard-free
    asm volatile("s_waitcnt lgkmcnt(0)" ::: "memory");
    __builtin_amdgcn_sched_barrier(0);
    __builtin_amdgcn_s_barrier();
    __builtin_amdgcn_sched_barrier(0);
  }
#undef LOADT
#undef STAGEW

  // ---- flush wave-private survivor lists to global (lane == wave-local q) ----
  {
    const int cnt = lcnt[wv][lane];
    const int qg = wv*64 + lane;
    cnt_g[qg*NCH + cid] = (unsigned)cnt;
    const int nc = min(cnt, CAPQ);
    unsigned long long* dst = seg_g + (size_t)(qg*NCH + cid)*CAPQ;
    for (int j = 0; j < nc; ++j) {
      unsigned long long lo = seg_lds[wv][lane][j][0];
      unsigned long long hi = seg_lds[wv][lane][j][1];
      dst[j] = lo | (hi << 32);
    }
  }
}

// ---------------------------------------------------------------------------
// Kernel 2: per-query gather of survivors -> exact top-16 -> vote.
// Self-check: overflow or <16 survivors -> set flag (triggers fallback).
// ---------------------------------------------------------------------------
__global__ __launch_bounds__(64) void gather_vote_kernel(
    const float* __restrict__ pdb,
    const unsigned long long* __restrict__ seg_g, const unsigned* __restrict__ cnt_g,
    int* __restrict__ out_label, float* __restrict__ out_s, int* __restrict__ flag)
{
  __shared__ float    cv[NCH*CAPQ];   // 3072
  __shared__ unsigned ci[NCH*CAPQ];
  const int q    = (int)blockIdx.x;
  const int lane = (int)threadIdx.x;

  bool over = false;
  int tot = 0;
  #pragma unroll
  for (int h = 0; h < NCH/64; ++h) {
    const int c = h*64 + lane;
    const int cnt = (int)cnt_g[q*NCH + c];
    over |= (cnt > CAPQ);
    const int nc = min(cnt, CAPQ);
    tot += nc;
    const unsigned long long* src = seg_g + (size_t)(q*NCH + c)*CAPQ;
    for (int j = 0; j < CAPQ; ++j) {
      float v = NEGF; unsigned idx = 0u;
      if (j < nc) {
        const unsigned long long e = src[j];
        v = __uint_as_float((unsigned)e);
        idx = (unsigned)(e >> 32);
      }
      cv[c*CAPQ + j] = v;
      ci[c*CAPQ + j] = idx;
    }
  }
  #pragma unroll
  for (int off = 32; off >= 1; off >>= 1) tot += __shfl_xor(tot, off);
  __syncthreads();

  float topv[TK]; int topid[TK];
  #pragma unroll
  for (int r = 0; r < TK; ++r) {
    float bv = NEGF; int bp = -1;
    #pragma unroll 4
    for (int j = 0; j < (NCH*CAPQ)/64; ++j) {
      const int p = j*64 + lane;
      const float v = cv[p];
      if (v > bv) { bv = v; bp = p; }
    }
    #pragma unroll
    for (int off = 32; off >= 1; off >>= 1) {
      const float ov = __shfl_xor(bv, off);
      const int   op = __shfl_xor(bp, off);
      if (ov > bv || (ov == bv && ((unsigned)op < (unsigned)bp))) { bv = ov; bp = op; }
    }
    topv[r] = bv;
    int id = -2;
    if (bp >= 0 && bv > NEGF) id = (int)pdb[(size_t)ci[bp]*PDBW + CDIM];
    topid[r] = id;
    if (lane == 0 && bp >= 0) cv[bp] = NEGF;
    __syncthreads();
  }

  if (lane == 0) {
    bool mk[TK];
    int nvalid = 0;
    #pragma unroll
    for (int i = 0; i < TK; ++i) {
      mk[i] = (topv[i] >= MIN_SIM_C) && (topid[i] >= 0);
      nvalid += mk[i] ? 1 : 0;
    }
    int maj = 0, majid = 0x7fffffff;
    for (int i = 0; i < TK; ++i) {
      if (!mk[i]) continue;
      int c = 0;
      for (int j = 0; j < TK; ++j) c += (mk[j] && topid[j] == topid[i]) ? 1 : 0;
      if (c > maj || (c == maj && topid[i] < majid)) { maj = c; majid = topid[i]; }
    }
    const float ratio = (float)maj / fmaxf((float)nvalid, 1.0f);
    const bool valid = (maj > 0) && (ratio >= MIN_VOTES_C);
    const int label = valid ? majid : -1;
    float s = 0.f;
    #pragma unroll
    for (int i = 0; i < TK; ++i)
      if (mk[i] && topid[i] == label) s = fmaxf(s, topv[i]);
    out_label[q] = label;
    out_s[q]     = s;
  }
  const bool bad = (__ballot(over) != 0ull) || (tot < TK);
  if (lane == 0 && bad) atomicOr(flag, 1);
}

// ---------------------------------------------------------------------------
// Fallback stage 1 (round-1, proven): gated on flag
// ---------------------------------------------------------------------------
__global__ __launch_bounds__(256, 2) void sims_topk1_kernel(
    const float* __restrict__ qd, const float* __restrict__ pdb,
    float* __restrict__ cand_val, unsigned int* __restrict__ cand_idx,
    const int* __restrict__ gate)
{
  if (gate && *gate == 0) return;
  __shared__ __align__(16) short db_lds[128 * 264];
  float* sims = (float*)db_lds;

  const int tid  = (int)threadIdx.x;
  const int lane = tid & 63;
  const int wv   = tid >> 6;
  const int cid   = (int)blockIdx.x;
  const int mtile = (int)blockIdx.y;

  bf16x8 aq[2][8];
  {
    const int l15 = lane & 15;
    const int kb  = (lane >> 4) << 3;
    #pragma unroll
    for (int fm = 0; fm < 2; ++fm) {
      const int row = mtile*128 + wv*32 + fm*16 + l15;
      #pragma unroll
      for (int kk = 0; kk < 8; ++kk) {
        const float* p = qd + (size_t)row*CDIM + kk*32 + kb;
        float4 x0 = *(const float4*)p;
        float4 x1 = *(const float4*)(p + 4);
        bf16x8 a;
        a[0]=f2bf(x0.x); a[1]=f2bf(x0.y); a[2]=f2bf(x0.z); a[3]=f2bf(x0.w);
        a[4]=f2bf(x1.x); a[5]=f2bf(x1.y); a[6]=f2bf(x1.z); a[7]=f2bf(x1.w);
        aq[fm][kk] = a;
      }
    }
  }

  float    tv[TK];
  unsigned ti[TK];
  #pragma unroll
  for (int i = 0; i < TK; ++i) { tv[i] = NEGF; ti[i] = 0u; }
  float minv = NEGF; int minp = 0;

  const int g0chunk = cid * 4096;
  const int q_l  = tid & 127;
  const int half = tid >> 7;

  for (int s = 0; s < 32; ++s) {
    const int g0 = g0chunk + s*128;
    {
      const int rb = tid >> 6;
      const int c4 = (tid & 63) << 2;
      for (int i = 0; i < 32; ++i) {
        const int rl = i*4 + rb;
        const int g  = g0 + rl;
        float v0, v1, v2, v3;
        if (g < NDB) {
          const float* p = pdb + (size_t)g*PDBW + c4;
          v0 = p[0]; v1 = p[1]; v2 = p[2]; v3 = p[3];
        } else { v0 = v1 = v2 = v3 = 0.f; }
        short* d = &db_lds[rl*264 + c4];
        d[0]=f2bf(v0); d[1]=f2bf(v1); d[2]=f2bf(v2); d[3]=f2bf(v3);
      }
    }
    __syncthreads();

    f32x4 acc[2][8];
    #pragma unroll
    for (int fm = 0; fm < 2; ++fm)
      #pragma unroll
      for (int fn = 0; fn < 8; ++fn)
        acc[fm][fn] = (f32x4){0.f, 0.f, 0.f, 0.f};
    {
      const int l15 = lane & 15;
      const int kb  = (lane >> 4) << 3;
      #pragma unroll
      for (int kk = 0; kk < 8; ++kk) {
        bf16x8 b[8];
        #pragma unroll
        for (int fn = 0; fn < 8; ++fn)
          b[fn] = *(const bf16x8*)&db_lds[(fn*16 + l15)*264 + kk*32 + kb];
        #pragma unroll
        for (int fn = 0; fn < 8; ++fn) {
          acc[0][fn] = __builtin_amdgcn_mfma_f32_16x16x32_bf16(aq[0][kk], b[fn], acc[0][fn], 0, 0, 0);
          acc[1][fn] = __builtin_amdgcn_mfma_f32_16x16x32_bf16(aq[1][kk], b[fn], acc[1][fn], 0, 0, 0);
        }
      }
    }
    __syncthreads();

    {
      const int colb = lane & 15;
      const int rowb = (lane >> 4) << 2;
      #pragma unroll
      for (int fm = 0; fm < 2; ++fm)
        #pragma unroll
        for (int fn = 0; fn < 8; ++fn)
          #pragma unroll
          for (int j = 0; j < 4; ++j)
            sims[(wv*32 + fm*16 + rowb + j)*129 + fn*16 + colb] = acc[fm][fn][j];
    }
    __syncthreads();

    {
      const int cb = half * 64;
      #pragma unroll 4
      for (int c = 0; c < 64; ++c) {
        const int colc = cb + c;
        const float v = sims[q_l*129 + colc];
        const int g = g0 + colc;
        if (v > minv && g < NDB) {
          #pragma unroll
          for (int i = 0; i < TK; ++i) if (i == minp) { tv[i] = v; ti[i] = (unsigned)g; }
          minv = tv[0]; minp = 0;
          #pragma unroll
          for (int i = 1; i < TK; ++i) if (tv[i] < minv) { minv = tv[i]; minp = i; }
        }
      }
    }
    __syncthreads();
  }

  {
    const int qg = mtile*128 + q_l;
    float*    pv = cand_val + ((size_t)qg*NCHUNK1 + cid)*32 + half*TK;
    unsigned* pi = cand_idx + ((size_t)qg*NCHUNK1 + cid)*32 + half*TK;
    #pragma unroll
    for (int i = 0; i < TK; ++i) { pv[i] = tv[i]; pi[i] = ti[i]; }
  }
}

// ---------------------------------------------------------------------------
// Fallback stage 2 (round-1, proven): gated on flag
// ---------------------------------------------------------------------------
template<int CPQ>
__global__ __launch_bounds__(64) void merge_vote_kernel(
    const float* __restrict__ pdb,
    const float* __restrict__ cand_val, const unsigned* __restrict__ cand_idx,
    int* __restrict__ out_label, float* __restrict__ out_s,
    const int* __restrict__ gate)
{
  if (gate && *gate == 0) return;
  __shared__ float    cv[CPQ];
  __shared__ unsigned ci[CPQ];
  const int q    = (int)blockIdx.x;
  const int lane = (int)threadIdx.x;

  for (int j = lane; j < CPQ; j += 64) {
    cv[j] = cand_val[(size_t)q*CPQ + j];
    ci[j] = cand_idx[(size_t)q*CPQ + j];
  }
  __syncthreads();

  float topv[TK]; int topid[TK];
  #pragma unroll
  for (int r = 0; r < TK; ++r) {
    float bv = NEGF; int bp = -1;
    for (int j = lane; j < CPQ; j += 64) {
      const float v = cv[j];
      if (v > bv) { bv = v; bp = j; }
    }
    #pragma unroll
    for (int off = 32; off >= 1; off >>= 1) {
      const float ov = __shfl_xor(bv, off);
      const int   op = __shfl_xor(bp, off);
      if (ov > bv || (ov == bv && ((unsigned)op < (unsigned)bp))) { bv = ov; bp = op; }
    }
    topv[r] = bv;
    int id = -2;
    if (bp >= 0 && bv > NEGF) id = (int)pdb[(size_t)ci[bp]*PDBW + CDIM];
    topid[r] = id;
    if (lane == 0 && bp >= 0) cv[bp] = NEGF;
    __syncthreads();
  }

  if (lane == 0) {
    bool mk[TK];
    int nvalid = 0;
    #pragma unroll
    for (int i = 0; i < TK; ++i) {
      mk[i] = (topv[i] >= MIN_SIM_C) && (topid[i] >= 0);
      nvalid += mk[i] ? 1 : 0;
    }
    int maj = 0, majid = 0x7fffffff;
    for (int i = 0; i < TK; ++i) {
      if (!mk[i]) continue;
      int c = 0;
      for (int j = 0; j < TK; ++j) c += (mk[j] && topid[j] == topid[i]) ? 1 : 0;
      if (c > maj || (c == maj && topid[i] < majid)) { maj = c; majid = topid[i]; }
    }
    const float ratio = (float)maj / fmaxf((float)nvalid, 1.0f);
    const bool valid = (maj > 0) && (ratio >= MIN_VOTES_C);
    const int label = valid ? majid : -1;
    float s = 0.f;
    #pragma unroll
    for (int i = 0; i < TK; ++i)
      if (mk[i] && topid[i] == label) s = fmaxf(s, topv[i]);
    out_label[q] = label;
    out_s[q]     = s;
  }
}

// ---------------------------------------------------------------------------
// Stage 3: overlap removal + final outputs
// ---------------------------------------------------------------------------
__device__ __forceinline__ bool finitef(float v) {
  return ((__float_as_uint(v) >> 23) & 0xffu) != 0xffu;
}

__global__ __launch_bounds__(64) void finalize_kernel(
    const float* __restrict__ boxes, const int* __restrict__ labels,
    const float* __restrict__ svals, float* __restrict__ out)
{
  const int x    = (int)blockIdx.x;
  const int lane = (int)threadIdx.x;
  const int lx = labels[x];
  const float bx1 = boxes[x*4+0], by1 = boxes[x*4+1];
  const float bx2 = boxes[x*4+2], by2 = boxes[x*4+3];
  const float ax = (bx2 - bx1) * (by2 - by1);

  bool flag = false;
  if (lx >= 0) {
    for (int y = lane; y < QN; y += 64) {
      if (y == x) continue;
      if (labels[y] != lx) continue;
      const float c1 = boxes[y*4+0], c2 = boxes[y*4+1];
      const float c3 = boxes[y*4+2], c4 = boxes[y*4+3];
      const float ay = (c3 - c1) * (c4 - c2);
      const float xi1 = fmaxf(bx1, c1), yi1 = fmaxf(by1, c2);
      const float xi2 = fminf(bx2, c3), yi2 = fminf(by2, c4);
      const float inter = fmaxf(xi2 - xi1, 0.f) * fmaxf(yi2 - yi1, 0.f);
      const float asmall = fminf(ax, ay);
      const float ov = (asmall > 0.f) ? inter / fmaxf(asmall, 1e-12f) : 0.f;
      if (ov >= 0.5f && ay <= ax) flag = true;
    }
  }
  const bool removed = (__ballot(flag) != 0ull);
  const int label = removed ? -1 : lx;
  const float s = svals[x];
  const bool fin = finitef(s) && finitef(bx1) && finitef(by1) && finitef(bx2) && finitef(by2);
  const bool valid = (label >= 0) && fin;

  if (lane == 0) {
    out[4096 + x] = valid ? s : 0.f;
    out[5120 + x] = (float)(valid ? label : -1);
  }
  if (lane < 4) out[x*4 + lane] = boxes[x*4 + lane];
}

// ---------------------------------------------------------------------------
extern "C" void kernel_launch(void* const* d_in, const int* in_sizes, int n_in,
                              void* d_out, int out_size, void* d_ws, size_t ws_size,
                              hipStream_t stream)
{
  const float* boxes = (const float*)d_in[0];
  const float* qd    = (const float*)d_in[1];
  const float* pdb   = (const float*)d_in[2];
  float* out = (float*)d_out;
  char* ws = (char*)d_ws;

  const size_t seg_bytes = (size_t)QN * NCH * CAPQ * 8;       //  25,165,824
  const size_t cnt_bytes = (size_t)QN * NCH * 4;              //   1,048,576
  const size_t c1_bytes  = (size_t)QN * CPQ1 * 8;             //  12,845,056 (fallback, aliases seg+cnt)
  const size_t A_bytes   = (seg_bytes + cnt_bytes > c1_bytes) ? seg_bytes + cnt_bytes : c1_bytes;
  const size_t need = A_bytes + (size_t)QN*8 + 64;

  if (ws_size >= need) {
    char* A = ws;
    unsigned long long* seg_g = (unsigned long long*)A;
    unsigned*           cnt_g = (unsigned*)(A + seg_bytes);
    float*    cand_val = (float*)A;
    unsigned* cand_idx = (unsigned*)(A + (size_t)QN*CPQ1*4);
    int*      labels   = (int*)(ws + A_bytes);
    float*    svals    = (float*)(ws + A_bytes + (size_t)QN*4);
    int*      flag     = (int*)(ws + A_bytes + (size_t)QN*8);

    hipLaunchKernelGGL(sims_fused_kernel, dim3(NCH), dim3(1024), 0, stream,
                       qd, pdb, seg_g, cnt_g, flag);
    hipLaunchKernelGGL(gather_vote_kernel, dim3(QN), dim3(64), 0, stream,
                       pdb, seg_g, cnt_g, labels, svals, flag);
    hipLaunchKernelGGL(sims_topk1_kernel, dim3(NCHUNK1, 8), dim3(256), 0, stream,
                       qd, pdb, cand_val, cand_idx, flag);
    hipLaunchKernelGGL((merge_vote_kernel<CPQ1>), dim3(QN), dim3(64), 0, stream,
                       pdb, cand_val, cand_idx, labels, svals, flag);
    hipLaunchKernelGGL(finalize_kernel, dim3(QN), dim3(64), 0, stream,
                       boxes, labels, svals, out);
  } else {
    const size_t n1 = (size_t)QN * CPQ1;
    float*    cand_val = (float*)ws;
    unsigned* cand_idx = (unsigned*)(ws + n1*4);
    int*      labels   = (int*)(ws + n1*8);
    float*    svals    = (float*)(ws + n1*8 + (size_t)QN*4);

    hipLaunchKernelGGL(sims_topk1_kernel, dim3(NCHUNK1, 8), dim3(256), 0, stream,
                       qd, pdb, cand_val, cand_idx, (const int*)nullptr);
    hipLaunchKernelGGL((merge_vote_kernel<CPQ1>), dim3(QN), dim3(64), 0, stream,
                       pdb, cand_val, cand_idx, labels, svals, (const int*)nullptr);
    hipLaunchKernelGGL(finalize_kernel, dim3(QN), dim3(64), 0, stream,
                       boxes, labels, svals, out);
  }
}

// Round 10
// 156.978 us; speedup vs baseline: 4.2233x; 4.2233x over previous
//
#include <hip/hip_runtime.h>
#include <hip/hip_bf16.h>

// ---------------- problem constants ----------------
#define QN 1024
#define NDB 200000
#define NDB_PAD 200064        // 3126 subtiles of 64 rows
#define PDBW 257
#define CDIM 256
#define TK 16
#define NEGF (-1e30f)
#define MIN_SIM_C 0.05f
#define MIN_VOTES_C 0.3f

// fused fast path: 128 chunks x 2 mtiles (512 thr, 8 waves x 64 q)
#define NCH 128
#define THETA 0.19f           // P(sim>THETA)=1.18e-3; true 16th-best ~0.236 (fp8 err ~3e-3 -> ~15 sigma)
#define CAPQ 14               // per-(query,chunk) cap (lambda~1.84, P(over)~1e-9/cell)
// fallback (round-1, proven) path
#define NCHUNK1 49
#define CPQ1 (NCHUNK1*32)

typedef __attribute__((ext_vector_type(8))) short bf16x8;
typedef __attribute__((ext_vector_type(4))) float f32x4;
typedef __attribute__((ext_vector_type(8))) int   i32x8;
typedef __attribute__((ext_vector_type(4))) int   i32x4;

__device__ __forceinline__ short f2bf(float f) {
  union { float f; unsigned u; } x; x.f = f;
  unsigned u = x.u;
  return (short)((u + 0x7fffu + ((u >> 16) & 1u)) >> 16);  // RNE
}

// pack 4 floats -> 4 fp8 e4m3 bytes (same converter feeds A and B, so any
// consistent lane-position->k mapping cancels in the MFMA dot product)
__device__ __forceinline__ unsigned pk_fp8x4(float a, float b, float c, float d) {
  unsigned w = (unsigned)__builtin_amdgcn_cvt_pk_fp8_f32(a, b, 0, false);
  w = (unsigned)__builtin_amdgcn_cvt_pk_fp8_f32(c, d, (int)w, true);
  return w;
}

// ---------------------------------------------------------------------------
// FUSED kernel: fp32 db -> fp8 reg-staging (swizzled ds_write, both-sides
// rule) + MX-fp8 MFMA + register theta-filter + wave-private LDS survivors.
// grid (128 chunks, 2 mtiles) = 256 blocks (1/CU), 512 thr (8 waves x 64 q).
// 512-thread block => 2 waves/SIMD => 256-VGPR budget: the ~190-reg live set
// (aq 64 + acc 64 + staging 32) fits WITHOUT scratch spill (round-9 lesson:
// 1024-thr block capped VGPR at 128 -> 2.1 GB scratch traffic).
// Per iter: STAGEW(s+1 from regs) | LOADT(s+2) | MFMA(s) | filter | barrier.
// LDS 90KB. db fp32 read 2x; mtile pair shares an XCD -> 2nd read ~L2-hit.
// ---------------------------------------------------------------------------
__global__ __launch_bounds__(512, 1) void sims_fused_kernel(
    const float* __restrict__ qd, const float* __restrict__ pdb,
    unsigned long long* __restrict__ seg_g, unsigned int* __restrict__ cnt_g,
    int* __restrict__ flag)
{
  __shared__ __align__(16) char db_lds[2][64 * 256];   // 32768 B (fp8, swizzled)
  __shared__ unsigned seg_lds[8][64][CAPQ][2];         // 57344 B (wave-private)
  __shared__ int lcnt[8][64];                          // 2048 B (wave-private)

  const int tid  = (int)threadIdx.x;
  const int lane = tid & 63;
  const int wv   = tid >> 6;          // 0..7
  const int cid  = (int)blockIdx.x;   // 0..127
  const int mt   = (int)blockIdx.y;   // 0..1
  // chunks 0..53 have 25 subtiles, 54..127 have 24 (covers 3126 subtiles)
  const int nsub = 24 + (cid < 54 ? 1 : 0);
  const int row0 = (24*cid + (cid < 54 ? cid : 54)) << 6;

  if (cid == 0 && mt == 0 && tid == 0) *flag = 0;
  lcnt[wv][lane] = 0;   // wave-private, no barrier needed

  const int l15  = lane & 15;
  const int egrp = lane >> 4;         // k-chunk group 0..3 (32 k each)
  const int rowb = egrp << 2;
  const int colb = l15;

  // staging geometry: thread -> (row-in-tile, 32-float piece); swizzled dest
  const int srow = tid >> 3;          // 0..63
  const int sp   = tid & 7;           // 0..7
  const int sg0  = ((2*sp    ) ^ (srow & 15)) << 4;   // granule byte offsets
  const int sg1  = ((2*sp + 1) ^ (srow & 15)) << 4;
  const int sbase = srow * 256;

  // ---- Q fragments: fp32 -> fp8 packed i32x8; wave wv owns 64 queries ----
  i32x8 aq[4][2];
  {
    #pragma unroll
    for (int fm = 0; fm < 4; ++fm) {
      const float* qrow = qd + (size_t)(mt*512 + wv*64 + fm*16 + l15)*CDIM;
      #pragma unroll
      for (int kk = 0; kk < 2; ++kk) {
        const float* p = qrow + kk*128 + egrp*32;
        i32x8 a;
        #pragma unroll
        for (int d = 0; d < 8; ++d) {
          float4 x = *(const float4*)(p + d*4);
          a[d] = (int)pk_fp8x4(x.x, x.y, x.z, x.w);
        }
        aq[fm][kk] = a;
      }
    }
  }

  float4 sf0, sf1, sf2, sf3, sf4, sf5, sf6, sf7;  // in-flight staging regs (128 B)
#define LOADT(tile) do { \
    const int _r = row0 + (tile)*64 + srow; \
    if (_r < NDB) { \
      const float* _p = pdb + (size_t)_r*PDBW + sp*32; \
      sf0 = *(const float4*)(_p);      sf1 = *(const float4*)(_p + 4); \
      sf2 = *(const float4*)(_p + 8);  sf3 = *(const float4*)(_p + 12); \
      sf4 = *(const float4*)(_p + 16); sf5 = *(const float4*)(_p + 20); \
      sf6 = *(const float4*)(_p + 24); sf7 = *(const float4*)(_p + 28); \
    } else { \
      sf0 = sf1 = sf2 = sf3 = sf4 = sf5 = sf6 = sf7 = (float4){0.f, 0.f, 0.f, 0.f}; \
    } \
  } while (0)
#define STAGEW(bufi) do { \
    i32x4 _w0, _w1; \
    _w0[0] = (int)pk_fp8x4(sf0.x, sf0.y, sf0.z, sf0.w); \
    _w0[1] = (int)pk_fp8x4(sf1.x, sf1.y, sf1.z, sf1.w); \
    _w0[2] = (int)pk_fp8x4(sf2.x, sf2.y, sf2.z, sf2.w); \
    _w0[3] = (int)pk_fp8x4(sf3.x, sf3.y, sf3.z, sf3.w); \
    _w1[0] = (int)pk_fp8x4(sf4.x, sf4.y, sf4.z, sf4.w); \
    _w1[1] = (int)pk_fp8x4(sf5.x, sf5.y, sf5.z, sf5.w); \
    _w1[2] = (int)pk_fp8x4(sf6.x, sf6.y, sf6.z, sf6.w); \
    _w1[3] = (int)pk_fp8x4(sf7.x, sf7.y, sf7.z, sf7.w); \
    *(i32x4*)(db_lds[(bufi)] + sbase + sg0) = _w0; \
    *(i32x4*)(db_lds[(bufi)] + sbase + sg1) = _w1; \
  } while (0)

  // prologue: tile 0 staged to buf0; tile 1 loads in flight
  LOADT(0);
  STAGEW(0);
  LOADT(1);
  __syncthreads();   // buf0 visible to all waves

  for (int s = 0; s < nsub; ++s) {
    // write tile s+1 into the buffer MFMA-read in iter s-1 (drained at the
    // last barrier); issue tile s+2 loads -- a full iteration to land
    if (s + 1 < nsub) {
      STAGEW((s + 1) & 1);             // waits (data-dep) on LOADT(s+1)
      if (s + 2 < nsub) LOADT(s + 2);
    }

    // ---- MFMA: 64q x 64db per wave, K=256 via 2x K=128 MX-fp8 (unit scale) ----
    f32x4 acc[4][4];
    #pragma unroll
    for (int fm = 0; fm < 4; ++fm)
      #pragma unroll
      for (int fn = 0; fn < 4; ++fn)
        acc[fm][fn] = (f32x4){0.f, 0.f, 0.f, 0.f};
    __builtin_amdgcn_s_setprio(1);
    {
      const char* dbt = (const char*)db_lds[s & 1];
      #pragma unroll
      for (int kk = 0; kk < 2; ++kk) {
        #pragma unroll
        for (int fn = 0; fn < 4; ++fn) {
          const char* rowp = dbt + (fn*16 + l15)*256;
          const int mbase = kk*8 + egrp*2;
          i32x4 lo = *(const i32x4*)(rowp + (((mbase    ) ^ l15) << 4));
          i32x4 hi = *(const i32x4*)(rowp + (((mbase + 1) ^ l15) << 4));
          i32x8 b = __builtin_shufflevector(lo, hi, 0, 1, 2, 3, 4, 5, 6, 7);
          #pragma unroll
          for (int fm = 0; fm < 4; ++fm)
            acc[fm][fn] = __builtin_amdgcn_mfma_scale_f32_16x16x128_f8f6f4(
                aq[fm][kk], b, acc[fm][fn],
                0 /*fmtA=fp8*/, 0 /*fmtB=fp8*/,
                0, 0x7F7F7F7Fu /*scaleA=1.0*/, 0, 0x7F7F7F7Fu /*scaleB=1.0*/);
        }
      }
    }
    __builtin_amdgcn_s_setprio(0);

    // ---- theta-filter on fragments; wave-private LDS append ----
    {
      const int idxbase = row0 + s*64;
      #pragma unroll
      for (int fm = 0; fm < 4; ++fm)
        #pragma unroll
        for (int fn = 0; fn < 4; ++fn) {
          const f32x4 a = acc[fm][fn];
          const float m = fmaxf(fmaxf(a[0], a[1]), fmaxf(a[2], a[3]));
          if (m > THETA) {
            #pragma unroll
            for (int j = 0; j < 4; ++j) {
              if (a[j] > THETA) {
                const int ql = fm*16 + rowb + j;
                const int slot = atomicAdd(&lcnt[wv][ql], 1);
                if (slot < CAPQ) {
                  seg_lds[wv][ql][slot][0] = __float_as_uint(a[j]);
                  seg_lds[wv][ql][slot][1] = (unsigned)(idxbase + fn*16 + colb);
                }
              }
            }
          }
        }
    }

    // drain own ds ops, then barrier: makes the buffer rotation hazard-free
    asm volatile("s_waitcnt lgkmcnt(0)" ::: "memory");
    __builtin_amdgcn_sched_barrier(0);
    __builtin_amdgcn_s_barrier();
    __builtin_amdgcn_sched_barrier(0);
  }
#undef LOADT
#undef STAGEW

  // ---- flush wave-private survivor lists to global (lane == wave-local q) ----
  {
    const int cnt = lcnt[wv][lane];
    const int qg = mt*512 + wv*64 + lane;
    cnt_g[qg*NCH + cid] = (unsigned)cnt;
    const int nc = min(cnt, CAPQ);
    unsigned long long* dst = seg_g + (size_t)(qg*NCH + cid)*CAPQ;
    for (int j = 0; j < nc; ++j) {
      unsigned long long lo = seg_lds[wv][lane][j][0];
      unsigned long long hi = seg_lds[wv][lane][j][1];
      dst[j] = lo | (hi << 32);
    }
  }
}

// ---------------------------------------------------------------------------
// Kernel 2: per-query gather of survivors -> exact top-16 -> vote.
// Self-check: overflow or <16 survivors -> set flag (triggers fallback).
// ---------------------------------------------------------------------------
__global__ __launch_bounds__(64) void gather_vote_kernel(
    const float* __restrict__ pdb,
    const unsigned long long* __restrict__ seg_g, const unsigned* __restrict__ cnt_g,
    int* __restrict__ out_label, float* __restrict__ out_s, int* __restrict__ flag)
{
  __shared__ float    cv[NCH*CAPQ];   // 1792
  __shared__ unsigned ci[NCH*CAPQ];
  const int q    = (int)blockIdx.x;
  const int lane = (int)threadIdx.x;

  bool over = false;
  int tot = 0;
  #pragma unroll
  for (int h = 0; h < NCH/64; ++h) {
    const int c = h*64 + lane;
    const int cnt = (int)cnt_g[q*NCH + c];
    over |= (cnt > CAPQ);
    const int nc = min(cnt, CAPQ);
    tot += nc;
    const unsigned long long* src = seg_g + (size_t)(q*NCH + c)*CAPQ;
    for (int j = 0; j < CAPQ; ++j) {
      float v = NEGF; unsigned idx = 0u;
      if (j < nc) {
        const unsigned long long e = src[j];
        v = __uint_as_float((unsigned)e);
        idx = (unsigned)(e >> 32);
      }
      cv[c*CAPQ + j] = v;
      ci[c*CAPQ + j] = idx;
    }
  }
  #pragma unroll
  for (int off = 32; off >= 1; off >>= 1) tot += __shfl_xor(tot, off);
  __syncthreads();

  float topv[TK]; int topid[TK];
  #pragma unroll
  for (int r = 0; r < TK; ++r) {
    float bv = NEGF; int bp = -1;
    #pragma unroll 4
    for (int j = 0; j < (NCH*CAPQ)/64; ++j) {
      const int p = j*64 + lane;
      const float v = cv[p];
      if (v > bv) { bv = v; bp = p; }
    }
    #pragma unroll
    for (int off = 32; off >= 1; off >>= 1) {
      const float ov = __shfl_xor(bv, off);
      const int   op = __shfl_xor(bp, off);
      if (ov > bv || (ov == bv && ((unsigned)op < (unsigned)bp))) { bv = ov; bp = op; }
    }
    topv[r] = bv;
    int id = -2;
    if (bp >= 0 && bv > NEGF) id = (int)pdb[(size_t)ci[bp]*PDBW + CDIM];
    topid[r] = id;
    if (lane == 0 && bp >= 0) cv[bp] = NEGF;
    __syncthreads();
  }

  if (lane == 0) {
    bool mk[TK];
    int nvalid = 0;
    #pragma unroll
    for (int i = 0; i < TK; ++i) {
      mk[i] = (topv[i] >= MIN_SIM_C) && (topid[i] >= 0);
      nvalid += mk[i] ? 1 : 0;
    }
    int maj = 0, majid = 0x7fffffff;
    for (int i = 0; i < TK; ++i) {
      if (!mk[i]) continue;
      int c = 0;
      for (int j = 0; j < TK; ++j) c += (mk[j] && topid[j] == topid[i]) ? 1 : 0;
      if (c > maj || (c == maj && topid[i] < majid)) { maj = c; majid = topid[i]; }
    }
    const float ratio = (float)maj / fmaxf((float)nvalid, 1.0f);
    const bool valid = (maj > 0) && (ratio >= MIN_VOTES_C);
    const int label = valid ? majid : -1;
    float s = 0.f;
    #pragma unroll
    for (int i = 0; i < TK; ++i)
      if (mk[i] && topid[i] == label) s = fmaxf(s, topv[i]);
    out_label[q] = label;
    out_s[q]     = s;
  }
  const bool bad = (__ballot(over) != 0ull) || (tot < TK);
  if (lane == 0 && bad) atomicOr(flag, 1);
}

// ---------------------------------------------------------------------------
// Fallback stage 1 (round-1, proven): gated on flag
// ---------------------------------------------------------------------------
__global__ __launch_bounds__(256, 2) void sims_topk1_kernel(
    const float* __restrict__ qd, const float* __restrict__ pdb,
    float* __restrict__ cand_val, unsigned int* __restrict__ cand_idx,
    const int* __restrict__ gate)
{
  if (gate && *gate == 0) return;
  __shared__ __align__(16) short db_lds[128 * 264];
  float* sims = (float*)db_lds;

  const int tid  = (int)threadIdx.x;
  const int lane = tid & 63;
  const int wv   = tid >> 6;
  const int cid   = (int)blockIdx.x;
  const int mtile = (int)blockIdx.y;

  bf16x8 aq[2][8];
  {
    const int l15 = lane & 15;
    const int kb  = (lane >> 4) << 3;
    #pragma unroll
    for (int fm = 0; fm < 2; ++fm) {
      const int row = mtile*128 + wv*32 + fm*16 + l15;
      #pragma unroll
      for (int kk = 0; kk < 8; ++kk) {
        const float* p = qd + (size_t)row*CDIM + kk*32 + kb;
        float4 x0 = *(const float4*)p;
        float4 x1 = *(const float4*)(p + 4);
        bf16x8 a;
        a[0]=f2bf(x0.x); a[1]=f2bf(x0.y); a[2]=f2bf(x0.z); a[3]=f2bf(x0.w);
        a[4]=f2bf(x1.x); a[5]=f2bf(x1.y); a[6]=f2bf(x1.z); a[7]=f2bf(x1.w);
        aq[fm][kk] = a;
      }
    }
  }

  float    tv[TK];
  unsigned ti[TK];
  #pragma unroll
  for (int i = 0; i < TK; ++i) { tv[i] = NEGF; ti[i] = 0u; }
  float minv = NEGF; int minp = 0;

  const int g0chunk = cid * 4096;
  const int q_l  = tid & 127;
  const int half = tid >> 7;

  for (int s = 0; s < 32; ++s) {
    const int g0 = g0chunk + s*128;
    {
      const int rb = tid >> 6;
      const int c4 = (tid & 63) << 2;
      for (int i = 0; i < 32; ++i) {
        const int rl = i*4 + rb;
        const int g  = g0 + rl;
        float v0, v1, v2, v3;
        if (g < NDB) {
          const float* p = pdb + (size_t)g*PDBW + c4;
          v0 = p[0]; v1 = p[1]; v2 = p[2]; v3 = p[3];
        } else { v0 = v1 = v2 = v3 = 0.f; }
        short* d = &db_lds[rl*264 + c4];
        d[0]=f2bf(v0); d[1]=f2bf(v1); d[2]=f2bf(v2); d[3]=f2bf(v3);
      }
    }
    __syncthreads();

    f32x4 acc[2][8];
    #pragma unroll
    for (int fm = 0; fm < 2; ++fm)
      #pragma unroll
      for (int fn = 0; fn < 8; ++fn)
        acc[fm][fn] = (f32x4){0.f, 0.f, 0.f, 0.f};
    {
      const int l15 = lane & 15;
      const int kb  = (lane >> 4) << 3;
      #pragma unroll
      for (int kk = 0; kk < 8; ++kk) {
        bf16x8 b[8];
        #pragma unroll
        for (int fn = 0; fn < 8; ++fn)
          b[fn] = *(const bf16x8*)&db_lds[(fn*16 + l15)*264 + kk*32 + kb];
        #pragma unroll
        for (int fn = 0; fn < 8; ++fn) {
          acc[0][fn] = __builtin_amdgcn_mfma_f32_16x16x32_bf16(aq[0][kk], b[fn], acc[0][fn], 0, 0, 0);
          acc[1][fn] = __builtin_amdgcn_mfma_f32_16x16x32_bf16(aq[1][kk], b[fn], acc[1][fn], 0, 0, 0);
        }
      }
    }
    __syncthreads();

    {
      const int colb = lane & 15;
      const int rowb = (lane >> 4) << 2;
      #pragma unroll
      for (int fm = 0; fm < 2; ++fm)
        #pragma unroll
        for (int fn = 0; fn < 8; ++fn)
          #pragma unroll
          for (int j = 0; j < 4; ++j)
            sims[(wv*32 + fm*16 + rowb + j)*129 + fn*16 + colb] = acc[fm][fn][j];
    }
    __syncthreads();

    {
      const int cb = half * 64;
      #pragma unroll 4
      for (int c = 0; c < 64; ++c) {
        const int colc = cb + c;
        const float v = sims[q_l*129 + colc];
        const int g = g0 + colc;
        if (v > minv && g < NDB) {
          #pragma unroll
          for (int i = 0; i < TK; ++i) if (i == minp) { tv[i] = v; ti[i] = (unsigned)g; }
          minv = tv[0]; minp = 0;
          #pragma unroll
          for (int i = 1; i < TK; ++i) if (tv[i] < minv) { minv = tv[i]; minp = i; }
        }
      }
    }
    __syncthreads();
  }

  {
    const int qg = mtile*128 + q_l;
    float*    pv = cand_val + ((size_t)qg*NCHUNK1 + cid)*32 + half*TK;
    unsigned* pi = cand_idx + ((size_t)qg*NCHUNK1 + cid)*32 + half*TK;
    #pragma unroll
    for (int i = 0; i < TK; ++i) { pv[i] = tv[i]; pi[i] = ti[i]; }
  }
}

// ---------------------------------------------------------------------------
// Fallback stage 2 (round-1, proven): gated on flag
// ---------------------------------------------------------------------------
template<int CPQ>
__global__ __launch_bounds__(64) void merge_vote_kernel(
    const float* __restrict__ pdb,
    const float* __restrict__ cand_val, const unsigned* __restrict__ cand_idx,
    int* __restrict__ out_label, float* __restrict__ out_s,
    const int* __restrict__ gate)
{
  if (gate && *gate == 0) return;
  __shared__ float    cv[CPQ];
  __shared__ unsigned ci[CPQ];
  const int q    = (int)blockIdx.x;
  const int lane = (int)threadIdx.x;

  for (int j = lane; j < CPQ; j += 64) {
    cv[j] = cand_val[(size_t)q*CPQ + j];
    ci[j] = cand_idx[(size_t)q*CPQ + j];
  }
  __syncthreads();

  float topv[TK]; int topid[TK];
  #pragma unroll
  for (int r = 0; r < TK; ++r) {
    float bv = NEGF; int bp = -1;
    for (int j = lane; j < CPQ; j += 64) {
      const float v = cv[j];
      if (v > bv) { bv = v; bp = j; }
    }
    #pragma unroll
    for (int off = 32; off >= 1; off >>= 1) {
      const float ov = __shfl_xor(bv, off);
      const int   op = __shfl_xor(bp, off);
      if (ov > bv || (ov == bv && ((unsigned)op < (unsigned)bp))) { bv = ov; bp = op; }
    }
    topv[r] = bv;
    int id = -2;
    if (bp >= 0 && bv > NEGF) id = (int)pdb[(size_t)ci[bp]*PDBW + CDIM];
    topid[r] = id;
    if (lane == 0 && bp >= 0) cv[bp] = NEGF;
    __syncthreads();
  }

  if (lane == 0) {
    bool mk[TK];
    int nvalid = 0;
    #pragma unroll
    for (int i = 0; i < TK; ++i) {
      mk[i] = (topv[i] >= MIN_SIM_C) && (topid[i] >= 0);
      nvalid += mk[i] ? 1 : 0;
    }
    int maj = 0, majid = 0x7fffffff;
    for (int i = 0; i < TK; ++i) {
      if (!mk[i]) continue;
      int c = 0;
      for (int j = 0; j < TK; ++j) c += (mk[j] && topid[j] == topid[i]) ? 1 : 0;
      if (c > maj || (c == maj && topid[i] < majid)) { maj = c; majid = topid[i]; }
    }
    const float ratio = (float)maj / fmaxf((float)nvalid, 1.0f);
    const bool valid = (maj > 0) && (ratio >= MIN_VOTES_C);
    const int label = valid ? majid : -1;
    float s = 0.f;
    #pragma unroll
    for (int i = 0; i < TK; ++i)
      if (mk[i] && topid[i] == label) s = fmaxf(s, topv[i]);
    out_label[q] = label;
    out_s[q]     = s;
  }
}

// ---------------------------------------------------------------------------
// Stage 3: overlap removal + final outputs
// ---------------------------------------------------------------------------
__device__ __forceinline__ bool finitef(float v) {
  return ((__float_as_uint(v) >> 23) & 0xffu) != 0xffu;
}

__global__ __launch_bounds__(64) void finalize_kernel(
    const float* __restrict__ boxes, const int* __restrict__ labels,
    const float* __restrict__ svals, float* __restrict__ out)
{
  const int x    = (int)blockIdx.x;
  const int lane = (int)threadIdx.x;
  const int lx = labels[x];
  const float bx1 = boxes[x*4+0], by1 = boxes[x*4+1];
  const float bx2 = boxes[x*4+2], by2 = boxes[x*4+3];
  const float ax = (bx2 - bx1) * (by2 - by1);

  bool flag = false;
  if (lx >= 0) {
    for (int y = lane; y < QN; y += 64) {
      if (y == x) continue;
      if (labels[y] != lx) continue;
      const float c1 = boxes[y*4+0], c2 = boxes[y*4+1];
      const float c3 = boxes[y*4+2], c4 = boxes[y*4+3];
      const float ay = (c3 - c1) * (c4 - c2);
      const float xi1 = fmaxf(bx1, c1), yi1 = fmaxf(by1, c2);
      const float xi2 = fminf(bx2, c3), yi2 = fminf(by2, c4);
      const float inter = fmaxf(xi2 - xi1, 0.f) * fmaxf(yi2 - yi1, 0.f);
      const float asmall = fminf(ax, ay);
      const float ov = (asmall > 0.f) ? inter / fmaxf(asmall, 1e-12f) : 0.f;
      if (ov >= 0.5f && ay <= ax) flag = true;
    }
  }
  const bool removed = (__ballot(flag) != 0ull);
  const int label = removed ? -1 : lx;
  const float s = svals[x];
  const bool fin = finitef(s) && finitef(bx1) && finitef(by1) && finitef(bx2) && finitef(by2);
  const bool valid = (label >= 0) && fin;

  if (lane == 0) {
    out[4096 + x] = valid ? s : 0.f;
    out[5120 + x] = (float)(valid ? label : -1);
  }
  if (lane < 4) out[x*4 + lane] = boxes[x*4 + lane];
}

// ---------------------------------------------------------------------------
extern "C" void kernel_launch(void* const* d_in, const int* in_sizes, int n_in,
                              void* d_out, int out_size, void* d_ws, size_t ws_size,
                              hipStream_t stream)
{
  const float* boxes = (const float*)d_in[0];
  const float* qd    = (const float*)d_in[1];
  const float* pdb   = (const float*)d_in[2];
  float* out = (float*)d_out;
  char* ws = (char*)d_ws;

  const size_t seg_bytes = (size_t)QN * NCH * CAPQ * 8;       //  14,680,064
  const size_t cnt_bytes = (size_t)QN * NCH * 4;              //     524,288
  const size_t c1_bytes  = (size_t)QN * CPQ1 * 8;             //  12,845,056 (fallback, aliases seg+cnt)
  const size_t A_bytes   = (seg_bytes + cnt_bytes > c1_bytes) ? seg_bytes + cnt_bytes : c1_bytes;
  const size_t need = A_bytes + (size_t)QN*8 + 64;

  if (ws_size >= need) {
    char* A = ws;
    unsigned long long* seg_g = (unsigned long long*)A;
    unsigned*           cnt_g = (unsigned*)(A + seg_bytes);
    float*    cand_val = (float*)A;
    unsigned* cand_idx = (unsigned*)(A + (size_t)QN*CPQ1*4);
    int*      labels   = (int*)(ws + A_bytes);
    float*    svals    = (float*)(ws + A_bytes + (size_t)QN*4);
    int*      flag     = (int*)(ws + A_bytes + (size_t)QN*8);

    hipLaunchKernelGGL(sims_fused_kernel, dim3(NCH, 2), dim3(512), 0, stream,
                       qd, pdb, seg_g, cnt_g, flag);
    hipLaunchKernelGGL(gather_vote_kernel, dim3(QN), dim3(64), 0, stream,
                       pdb, seg_g, cnt_g, labels, svals, flag);
    hipLaunchKernelGGL(sims_topk1_kernel, dim3(NCHUNK1, 8), dim3(256), 0, stream,
                       qd, pdb, cand_val, cand_idx, flag);
    hipLaunchKernelGGL((merge_vote_kernel<CPQ1>), dim3(QN), dim3(64), 0, stream,
                       pdb, cand_val, cand_idx, labels, svals, flag);
    hipLaunchKernelGGL(finalize_kernel, dim3(QN), dim3(64), 0, stream,
                       boxes, labels, svals, out);
  } else {
    const size_t n1 = (size_t)QN * CPQ1;
    float*    cand_val = (float*)ws;
    unsigned* cand_idx = (unsigned*)(ws + n1*4);
    int*      labels   = (int*)(ws + n1*8);
    float*    svals    = (float*)(ws + n1*8 + (size_t)QN*4);

    hipLaunchKernelGGL(sims_topk1_kernel, dim3(NCHUNK1, 8), dim3(256), 0, stream,
                       qd, pdb, cand_val, cand_idx, (const int*)nullptr);
    hipLaunchKernelGGL((merge_vote_kernel<CPQ1>), dim3(QN), dim3(64), 0, stream,
                       pdb, cand_val, cand_idx, labels, svals, (const int*)nullptr);
    hipLaunchKernelGGL(finalize_kernel, dim3(QN), dim3(64), 0, stream,
                       boxes, labels, svals, out);
  }
}